// Round 1
// baseline (330.626 us; speedup 1.0000x reference)
//
#include <hip/hip_runtime.h>

// conv2d NCHW/OIHW, stride 1, VALID. x=(64,3,256,256) f32, w=(16,3,3,3), b=(16)
// out=(64,16,254,254) f32.
// Memory-bound: 264 MB write + 50 MB read ≈ 50 us floor at 6.3 TB/s.
// Each thread: 2 consecutive ow pixels x all 16 oc. Weights via uniform
// (scalar-pipe) loads -- free relative to VALU. float2 stores (row stride
// 1016 B is 8B-aligned, not 16B, so float2 is widest safe vector store).

constexpr int N = 64, C = 3, H = 256, W = 256;
constexpr int OC = 16, K = 3, OH = 254, OW = 254;
constexpr int PW = OW / 2;  // 127 pixel-pairs per output row

__global__ __launch_bounds__(256) void conv3x3_kernel(
    const float* __restrict__ x, const float* __restrict__ w,
    const float* __restrict__ bias, float* __restrict__ out)
{
    int idx = blockIdx.x * blockDim.x + threadIdx.x;
    constexpr int total = N * OH * PW;
    if (idx >= total) return;

    int pw = idx % PW;          // which pixel pair in the row
    int t  = idx / PW;
    int oh = t % OH;
    int n  = t / OH;
    int ow = pw * 2;

    float acc0[OC], acc1[OC];
    #pragma unroll
    for (int oc = 0; oc < OC; ++oc) {
        float b = bias[oc];     // uniform -> scalar load
        acc0[oc] = b;
        acc1[oc] = b;
    }

    const float* xb = x + (size_t)n * C * H * W;

    #pragma unroll
    for (int c = 0; c < C; ++c) {
        #pragma unroll
        for (int kh = 0; kh < K; ++kh) {
            const float* xr = xb + ((size_t)c * H + (oh + kh)) * W + ow;
            // 4 input columns cover both pixels' 3-wide windows
            float i0 = xr[0], i1 = xr[1], i2 = xr[2], i3 = xr[3];
            #pragma unroll
            for (int oc = 0; oc < OC; ++oc) {
                // uniform indices -> s_load on scalar pipe, no VALU cost
                float w0 = w[((oc * C + c) * K + kh) * K + 0];
                float w1 = w[((oc * C + c) * K + kh) * K + 1];
                float w2 = w[((oc * C + c) * K + kh) * K + 2];
                acc0[oc] += i0 * w0 + i1 * w1 + i2 * w2;
                acc1[oc] += i1 * w0 + i2 * w1 + i3 * w2;
            }
        }
    }

    float* ob = out + ((size_t)n * OC * OH + oh) * OW + ow;
    #pragma unroll
    for (int oc = 0; oc < OC; ++oc) {
        float2 v = make_float2(acc0[oc], acc1[oc]);
        *reinterpret_cast<float2*>(ob + (size_t)oc * OH * OW) = v;
    }
}

extern "C" void kernel_launch(void* const* d_in, const int* in_sizes, int n_in,
                              void* d_out, int out_size, void* d_ws, size_t ws_size,
                              hipStream_t stream) {
    const float* x    = (const float*)d_in[0];
    const float* w    = (const float*)d_in[1];
    const float* bias = (const float*)d_in[2];
    float* out        = (float*)d_out;

    constexpr int total  = N * OH * PW;
    constexpr int block  = 256;
    constexpr int blocks = (total + block - 1) / block;
    conv3x3_kernel<<<blocks, block, 0, stream>>>(x, w, bias, out);
}